// Round 1
// baseline (443.492 us; speedup 1.0000x reference)
//
#include <hip/hip_runtime.h>
#include <hip/hip_bf16.h>
#include <stdint.h>

// B=8, S=1024, NX=1024, H=16, D=64
typedef __bf16 bf16x8 __attribute__((ext_vector_type(8)));
typedef float  f32x4  __attribute__((ext_vector_type(4)));

__device__ __forceinline__ void gload_lds16(const void* g, void* l) {
  __builtin_amdgcn_global_load_lds(
      (const __attribute__((address_space(1))) unsigned int*)g,
      (__attribute__((address_space(3))) unsigned int*)l, 16, 0, 0);
}

// ---------------- cast fp32 -> bf16, 4 elems/thread ----------------
__global__ void k_cast(const float* __restrict__ in, __bf16* __restrict__ out, int n4) {
  int i = blockIdx.x * blockDim.x + threadIdx.x;
  if (i >= n4) return;
  float4 v = reinterpret_cast<const float4*>(in)[i];
  union { __bf16 h[4]; uint64_t u; } c;
  c.h[0] = (__bf16)v.x; c.h[1] = (__bf16)v.y; c.h[2] = (__bf16)v.z; c.h[3] = (__bf16)v.w;
  *reinterpret_cast<uint64_t*>(out + 4l * i) = c.u;
}

// ------------- transpose fp32 [R][C] -> bf16 [C][R] ----------------
__global__ void k_transpose_cast(const float* __restrict__ in, __bf16* __restrict__ out,
                                 int R, int C) {
  __shared__ float t[32][33];
  const int tx = threadIdx.x & 31, ty = threadIdx.x >> 5;  // 32 x 8
  const int c0 = blockIdx.x * 32, r0 = blockIdx.y * 32;
#pragma unroll
  for (int rr = 0; rr < 4; ++rr)
    t[ty * 4 + rr][tx] = in[(long)(r0 + ty * 4 + rr) * C + c0 + tx];
  __syncthreads();
#pragma unroll
  for (int rr = 0; rr < 4; ++rr)
    out[(long)(c0 + ty * 4 + rr) * R + r0 + tx] = (__bf16)t[tx][ty * 4 + rr];
}

// ---------------- GEMM C = A[M,K] * Bt[N,K]^T + bias ----------------
// 128x128 tile, BK=32, 4 waves (2x2), 16x16x32 bf16 MFMA, global_load_lds staging.
// MODE 0: scatter epilogue -> q[B,H,S,D], k[B,H,S,D], v^T[B,H,D,S] (all bf16)
// MODE 1: fp32 epilogue -> fo[M,N]
template <int MODE>
__global__ void k_gemm_bt(const __bf16* __restrict__ A, const __bf16* __restrict__ Bt,
                          const float* __restrict__ bias, int M, int N, int K,
                          __bf16* __restrict__ qo, __bf16* __restrict__ ko,
                          __bf16* __restrict__ vo, float* __restrict__ fo) {
  __shared__ __bf16 Ab[128 * 32];
  __shared__ __bf16 Bb[128 * 32];
  const int l = threadIdx.x & 63, w = threadIdx.x >> 6;
  const int wr = w >> 1, wc = w & 1;
  const int bm = blockIdx.y, bn = blockIdx.x;

  f32x4 acc[4][4] = {};

  // staging: wave w, instr i covers LDS bytes [w*2048 + i*1024, +1024), lane l -> +l*16
  const __bf16* Ag = A + (long)(bm * 128 + w * 32 + (l >> 2)) * K + (l & 3) * 8;
  const __bf16* Bg = Bt + (long)(bn * 128 + w * 32 + (l >> 2)) * K + (l & 3) * 8;
  char* Al = (char*)Ab + w * 2048;
  char* Bl = (char*)Bb + w * 2048;

  for (int k0 = 0; k0 < K; k0 += 32) {
    gload_lds16(Ag + k0, Al);
    gload_lds16(Ag + 16l * K + k0, Al + 1024);
    gload_lds16(Bg + k0, Bl);
    gload_lds16(Bg + 16l * K + k0, Bl + 1024);
    __syncthreads();  // staging (vmcnt) drained by barrier

    bf16x8 af[4], bfr[4];
#pragma unroll
    for (int mi = 0; mi < 4; ++mi)
      af[mi] = *(const bf16x8*)&Ab[(wr * 64 + mi * 16 + (l & 15)) * 32 + ((l >> 4) << 3)];
#pragma unroll
    for (int ni = 0; ni < 4; ++ni)
      bfr[ni] = *(const bf16x8*)&Bb[(wc * 64 + ni * 16 + (l & 15)) * 32 + ((l >> 4) << 3)];
#pragma unroll
    for (int mi = 0; mi < 4; ++mi)
#pragma unroll
      for (int ni = 0; ni < 4; ++ni)
        acc[mi][ni] = __builtin_amdgcn_mfma_f32_16x16x32_bf16(af[mi], bfr[ni], acc[mi][ni], 0, 0, 0);
    __syncthreads();  // reads done before next stage overwrites
  }

  // D layout: row=(l>>4)*4+i, col=l&15  [measured m89/m91]
  if (MODE == 0) {
#pragma unroll
    for (int ni = 0; ni < 4; ++ni) {
      const int c = bn * 128 + wc * 64 + ni * 16 + (l & 15);
      const float bv = bias[c];
      const int which = c >> 10, cc = c & 1023, h = cc >> 6, d = cc & 63;
#pragma unroll
      for (int mi = 0; mi < 4; ++mi)
#pragma unroll
        for (int i = 0; i < 4; ++i) {
          const int r = bm * 128 + wr * 64 + mi * 16 + ((l >> 4) << 2) + i;
          const int b = r >> 10, s_ = r & 1023;
          const __bf16 v = (__bf16)(acc[mi][ni][i] + bv);
          const long hb = (long)(b * 16 + h);
          if (which == 0)      qo[(hb * 1024 + s_) * 64 + d] = v;
          else if (which == 1) ko[(hb * 1024 + s_) * 64 + d] = v;
          else                 vo[(hb * 64 + d) * 1024 + s_] = v;
        }
    }
  } else {
#pragma unroll
    for (int ni = 0; ni < 4; ++ni) {
      const int c = bn * 128 + wc * 64 + ni * 16 + (l & 15);
      const float bv = bias[c];
#pragma unroll
      for (int mi = 0; mi < 4; ++mi)
#pragma unroll
        for (int i = 0; i < 4; ++i) {
          const int r = bm * 128 + wr * 64 + mi * 16 + ((l >> 4) << 2) + i;
          fo[(long)r * N + c] = acc[mi][ni][i] + bv;
        }
    }
  }
}

// ---------------- causal flash attention ----------------
// grid (S/64, B*H); 4 waves/block, each wave owns 16 q-rows independently.
// q,k: [B,H,S,D] bf16; vt: [B,H,D,S] bf16; out: [B,S,NX] bf16.
__global__ void k_attn(const __bf16* __restrict__ qb, const __bf16* __restrict__ kb,
                       const __bf16* __restrict__ vtb, __bf16* __restrict__ ob) {
  __shared__ __bf16 plds[4][16 * 40];  // per-wave P tile, row stride 40 (16B-aligned b128 reads)
  const int l = threadIdx.x & 63, w = threadIdx.x >> 6;
  const int lm = l & 15, lg = l >> 4;
  const int bh = blockIdx.y;
  const int qbase = blockIdx.x * 64 + w * 16;
  const int b = bh >> 4, h = bh & 15;
  const __bf16* Q = qb + (long)bh * 65536;
  const __bf16* Kh = kb + (long)bh * 65536;
  const __bf16* Vt = vtb + (long)bh * 65536;
  __bf16* pl = plds[w];

  // Q fragments (A operand): row=lm, k=d=ds*32+lg*8+j  -- held in regs for all tiles
  bf16x8 qf[2];
#pragma unroll
  for (int ds = 0; ds < 2; ++ds)
    qf[ds] = *(const bf16x8*)(Q + (long)(qbase + lm) * 64 + ds * 32 + lg * 8);

  f32x4 oacc[4] = {};
  float m[4], s[4];
#pragma unroll
  for (int i = 0; i < 4; ++i) { m[i] = -__builtin_inff(); s[i] = 0.f; }

  const int ktiles = (qbase + 47) >> 5;  // causal: keys up to qbase+15
  for (int kt = 0; kt < ktiles; ++kt) {
    const int k0 = kt * 32;
    f32x4 sc0 = {}, sc1 = {};
#pragma unroll
    for (int ds = 0; ds < 2; ++ds) {
      bf16x8 kf0 = *(const bf16x8*)(Kh + (long)(k0 + lm) * 64 + ds * 32 + lg * 8);
      bf16x8 kf1 = *(const bf16x8*)(Kh + (long)(k0 + 16 + lm) * 64 + ds * 32 + lg * 8);
      sc0 = __builtin_amdgcn_mfma_f32_16x16x32_bf16(qf[ds], kf0, sc0, 0, 0, 0);
      sc1 = __builtin_amdgcn_mfma_f32_16x16x32_bf16(qf[ds], kf1, sc1, 0, 0, 0);
    }
    const bool needmask = (k0 + 31 > qbase);
    f32x4 p0, p1;
#pragma unroll
    for (int i = 0; i < 4; ++i) {
      sc0[i] *= 0.125f;  // 1/sqrt(64)
      sc1[i] *= 0.125f;
      if (needmask) {
        const int qg = qbase + lg * 4 + i;
        if (k0 + lm > qg)      sc0[i] = -__builtin_inff();
        if (k0 + 16 + lm > qg) sc1[i] = -__builtin_inff();
      }
      float tm = fmaxf(sc0[i], sc1[i]);
      tm = fmaxf(tm, __shfl_xor(tm, 1));
      tm = fmaxf(tm, __shfl_xor(tm, 2));
      tm = fmaxf(tm, __shfl_xor(tm, 4));
      tm = fmaxf(tm, __shfl_xor(tm, 8));
      const float mn = fmaxf(m[i], tm);
      const float fac = __expf(m[i] - mn);  // m=-inf first tile -> fac=0
      m[i] = mn;
      p0[i] = __expf(sc0[i] - mn);
      p1[i] = __expf(sc1[i] - mn);
      float ts = p0[i] + p1[i];
      ts += __shfl_xor(ts, 1);
      ts += __shfl_xor(ts, 2);
      ts += __shfl_xor(ts, 4);
      ts += __shfl_xor(ts, 8);
      s[i] = s[i] * fac + ts;
#pragma unroll
      for (int nf = 0; nf < 4; ++nf) oacc[nf][i] *= fac;
      // P transpose through LDS: write at (row=q, col=k), read as A-frag
      pl[(lg * 4 + i) * 40 + lm]      = (__bf16)p0[i];
      pl[(lg * 4 + i) * 40 + 16 + lm] = (__bf16)p1[i];
    }
    const bf16x8 pa = *(const bf16x8*)&pl[lm * 40 + lg * 8];  // P[q=lm][k=lg*8+j]
#pragma unroll
    for (int nf = 0; nf < 4; ++nf) {
      bf16x8 vf = *(const bf16x8*)(Vt + (long)(nf * 16 + lm) * 1024 + k0 + lg * 8);
      oacc[nf] = __builtin_amdgcn_mfma_f32_16x16x32_bf16(pa, vf, oacc[nf], 0, 0, 0);
    }
  }
#pragma unroll
  for (int nf = 0; nf < 4; ++nf)
#pragma unroll
    for (int i = 0; i < 4; ++i) {
      const int qg = qbase + lg * 4 + i;
      ob[((long)(b * 1024 + qg)) * 1024 + h * 64 + nf * 16 + lm] = (__bf16)(oacc[nf][i] / s[i]);
    }
}

extern "C" void kernel_launch(void* const* d_in, const int* in_sizes, int n_in,
                              void* d_out, int out_size, void* d_ws, size_t ws_size,
                              hipStream_t stream) {
  const float* x      = (const float*)d_in[0];
  const float* w_attn = (const float*)d_in[1];
  const float* b_attn = (const float*)d_in[2];
  const float* w_proj = (const float*)d_in[3];
  const float* b_proj = (const float*)d_in[4];
  float* out = (float*)d_out;

  char* ws = (char*)d_ws;
  const size_t SZ_XBF = (size_t)8192 * 1024 * 2;   // 16.8 MB
  __bf16* x_bf = (__bf16*)ws;  ws += SZ_XBF;
  __bf16* wat  = (__bf16*)ws;  ws += (size_t)3072 * 1024 * 2;
  __bf16* wpt  = (__bf16*)ws;  ws += (size_t)1024 * 1024 * 2;
  __bf16* qb   = (__bf16*)ws;  ws += SZ_XBF;       // [B,H,S,D]
  __bf16* kb   = (__bf16*)ws;  ws += SZ_XBF;       // [B,H,S,D]
  __bf16* vtb  = (__bf16*)ws;  ws += SZ_XBF;       // [B,H,D,S]
  __bf16* obf  = (__bf16*)ws;  ws += SZ_XBF;       // [B,S,NX]
  // total ws use: ~92.3 MB

  k_cast<<<8192, 256, 0, stream>>>(x, x_bf, 2097152);
  k_transpose_cast<<<dim3(96, 32), 256, 0, stream>>>(w_attn, wat, 1024, 3072);
  k_transpose_cast<<<dim3(32, 32), 256, 0, stream>>>(w_proj, wpt, 1024, 1024);
  k_gemm_bt<0><<<dim3(24, 64), 256, 0, stream>>>(x_bf, wat, b_attn, 8192, 3072, 1024,
                                                 qb, kb, vtb, nullptr);
  k_attn<<<dim3(16, 128), 256, 0, stream>>>(qb, kb, vtb, obf);
  k_gemm_bt<1><<<dim3(8, 64), 256, 0, stream>>>(obf, wpt, b_proj, 8192, 1024, 1024,
                                                nullptr, nullptr, nullptr, out);
}

// Round 2
// 286.871 us; speedup vs baseline: 1.5460x; 1.5460x over previous
//
#include <hip/hip_runtime.h>
#include <hip/hip_bf16.h>
#include <stdint.h>

// B=8, S=1024, NX=1024, H=16, D=64
typedef __bf16 bf16x8 __attribute__((ext_vector_type(8)));
typedef float  f32x4  __attribute__((ext_vector_type(4)));
typedef float  f32x16 __attribute__((ext_vector_type(16)));

__device__ __forceinline__ void gload_lds16(const void* g, void* l) {
  __builtin_amdgcn_global_load_lds(
      (const __attribute__((address_space(1))) unsigned int*)g,
      (__attribute__((address_space(3))) unsigned int*)l, 16, 0, 0);
}

// ---------------- cast fp32 -> bf16, 4 elems/thread ----------------
__global__ void k_cast(const float* __restrict__ in, __bf16* __restrict__ out, int n4) {
  int i = blockIdx.x * blockDim.x + threadIdx.x;
  if (i >= n4) return;
  float4 v = reinterpret_cast<const float4*>(in)[i];
  union { __bf16 h[4]; uint64_t u; } c;
  c.h[0] = (__bf16)v.x; c.h[1] = (__bf16)v.y; c.h[2] = (__bf16)v.z; c.h[3] = (__bf16)v.w;
  *reinterpret_cast<uint64_t*>(out + 4l * i) = c.u;
}

// ------------- transpose fp32 [R][C] -> bf16 [C][R] ----------------
__global__ void k_transpose_cast(const float* __restrict__ in, __bf16* __restrict__ out,
                                 int R, int C) {
  __shared__ float t[32][33];
  const int tx = threadIdx.x & 31, ty = threadIdx.x >> 5;  // 32 x 8
  const int c0 = blockIdx.x * 32, r0 = blockIdx.y * 32;
#pragma unroll
  for (int rr = 0; rr < 4; ++rr)
    t[ty * 4 + rr][tx] = in[(long)(r0 + ty * 4 + rr) * C + c0 + tx];
  __syncthreads();
#pragma unroll
  for (int rr = 0; rr < 4; ++rr)
    out[(long)(c0 + ty * 4 + rr) * R + r0 + tx] = (__bf16)t[tx][ty * 4 + rr];
}

// ---------------- GEMM C = A[M,K] * Bt[N,K]^T + bias ----------------
// 128x128 tile, BK=32, 4 waves (2x2), 16x16x32 bf16 MFMA, global_load_lds staging.
// MODE 0: scatter epilogue -> q[B,H,S,D] (pre-scaled 1/8), k[B,H,S,D], v^T[B,H,D,S]
// MODE 1: fp32 epilogue -> fo[M,N]
template <int MODE>
__global__ void k_gemm_bt(const __bf16* __restrict__ A, const __bf16* __restrict__ Bt,
                          const float* __restrict__ bias, int M, int N, int K,
                          __bf16* __restrict__ qo, __bf16* __restrict__ ko,
                          __bf16* __restrict__ vo, float* __restrict__ fo) {
  __shared__ __bf16 Ab[128 * 32];
  __shared__ __bf16 Bb[128 * 32];
  const int l = threadIdx.x & 63, w = threadIdx.x >> 6;
  const int wr = w >> 1, wc = w & 1;
  const int bm = blockIdx.y, bn = blockIdx.x;

  f32x4 acc[4][4] = {};

  const __bf16* Ag = A + (long)(bm * 128 + w * 32 + (l >> 2)) * K + (l & 3) * 8;
  const __bf16* Bg = Bt + (long)(bn * 128 + w * 32 + (l >> 2)) * K + (l & 3) * 8;
  char* Al = (char*)Ab + w * 2048;
  char* Bl = (char*)Bb + w * 2048;

  for (int k0 = 0; k0 < K; k0 += 32) {
    gload_lds16(Ag + k0, Al);
    gload_lds16(Ag + 16l * K + k0, Al + 1024);
    gload_lds16(Bg + k0, Bl);
    gload_lds16(Bg + 16l * K + k0, Bl + 1024);
    __syncthreads();

    bf16x8 af[4], bfr[4];
#pragma unroll
    for (int mi = 0; mi < 4; ++mi)
      af[mi] = *(const bf16x8*)&Ab[(wr * 64 + mi * 16 + (l & 15)) * 32 + ((l >> 4) << 3)];
#pragma unroll
    for (int ni = 0; ni < 4; ++ni)
      bfr[ni] = *(const bf16x8*)&Bb[(wc * 64 + ni * 16 + (l & 15)) * 32 + ((l >> 4) << 3)];
#pragma unroll
    for (int mi = 0; mi < 4; ++mi)
#pragma unroll
      for (int ni = 0; ni < 4; ++ni)
        acc[mi][ni] = __builtin_amdgcn_mfma_f32_16x16x32_bf16(af[mi], bfr[ni], acc[mi][ni], 0, 0, 0);
    __syncthreads();
  }

  if (MODE == 0) {
#pragma unroll
    for (int ni = 0; ni < 4; ++ni) {
      const int c = bn * 128 + wc * 64 + ni * 16 + (l & 15);
      const float bv = bias[c];
      const int which = c >> 10, cc = c & 1023, h = cc >> 6, d = cc & 63;
#pragma unroll
      for (int mi = 0; mi < 4; ++mi)
#pragma unroll
        for (int i = 0; i < 4; ++i) {
          const int r = bm * 128 + wr * 64 + mi * 16 + ((l >> 4) << 2) + i;
          const int b = r >> 10, s_ = r & 1023;
          float fv = acc[mi][ni][i] + bv;
          if (which == 0) fv *= 0.125f;  // fold 1/sqrt(D) into Q
          const __bf16 v = (__bf16)fv;
          const long hb = (long)(b * 16 + h);
          if (which == 0)      qo[(hb * 1024 + s_) * 64 + d] = v;
          else if (which == 1) ko[(hb * 1024 + s_) * 64 + d] = v;
          else                 vo[(hb * 64 + d) * 1024 + s_] = v;
        }
    }
  } else {
#pragma unroll
    for (int ni = 0; ni < 4; ++ni) {
      const int c = bn * 128 + wc * 64 + ni * 16 + (l & 15);
      const float bv = bias[c];
#pragma unroll
      for (int mi = 0; mi < 4; ++mi)
#pragma unroll
        for (int i = 0; i < 4; ++i) {
          const int r = bm * 128 + wr * 64 + mi * 16 + ((l >> 4) << 2) + i;
          fo[(long)r * N + c] = acc[mi][ni][i] + bv;
        }
    }
  }
}

// ---------------- causal flash attention, 32x32 swapped-QK^T, no LDS ----------------
// Per wave: one 32-row q-tile. ST = mfma(K, Q): lane owns q = qtile+ (l&31),
// holds ST for 16 keys krow(r,hi) = (r&3)+8*(r>>2)+4*hi. Softmax fully in-register.
// P repacked to PV A-frags with 8 bf16 packs + 4 shfl_xor(32).
__device__ __forceinline__ void attn_qtile(const __bf16* __restrict__ Q,
                                           const __bf16* __restrict__ Kh,
                                           const __bf16* __restrict__ Vt,
                                           __bf16* __restrict__ ob,
                                           int b, int h, int qbw, int l) {
  const int lm = l & 31, hi = l >> 5;

  bf16x8 qf[4];
#pragma unroll
  for (int ds = 0; ds < 4; ++ds)
    qf[ds] = *(const bf16x8*)(Q + (long)(qbw + lm) * 64 + ds * 16 + hi * 8);

  f32x16 oacc0 = {}, oacc1 = {};
  float m = -__builtin_inff(), s = 0.f;

  const int ntiles = (qbw >> 5) + 1;
  for (int kt = 0; kt < ntiles; ++kt) {
    const int k0 = kt * 32;
    // ---- QK^T (swapped): ST[key][q] ----
    f32x16 st = {};
#pragma unroll
    for (int ds = 0; ds < 4; ++ds) {
      bf16x8 kf = *(const bf16x8*)(Kh + (long)(k0 + lm) * 64 + ds * 16 + hi * 8);
      st = __builtin_amdgcn_mfma_f32_32x32x16_bf16(kf, qf[ds], st, 0, 0, 0);
    }
    // ---- causal mask (diagonal tile only) ----
    if (kt == ntiles - 1) {
      const int q = qbw + lm;
#pragma unroll
      for (int r = 0; r < 16; ++r) {
        const int key = k0 + (r & 3) + 8 * (r >> 2) + 4 * hi;
        if (key > q) st[r] = -__builtin_inff();
      }
    }
    // ---- online softmax, in-register ----
    float tm = st[0];
#pragma unroll
    for (int r = 1; r < 16; ++r) tm = fmaxf(tm, st[r]);
    tm = fmaxf(tm, __shfl_xor(tm, 32));
    if (!__all(tm <= m + 8.f)) {   // defer-max: rescale only on real growth
      const float mn = fmaxf(m, tm);
      const float fac = __expf(m - mn);  // first tile: exp(-inf)=0
      m = mn;
      s *= fac;
#pragma unroll
      for (int r = 0; r < 16; ++r) {
        const int qr = (r & 3) + 8 * (r >> 2) + 4 * hi;
        const float fr = __int_as_float(
            __builtin_amdgcn_ds_bpermute(qr * 4, __float_as_int(fac)));
        oacc0[r] *= fr; oacc1[r] *= fr;
      }
    }
    float p[16], ts = 0.f;
#pragma unroll
    for (int r = 0; r < 16; ++r) { p[r] = __expf(st[r] - m); ts += p[r]; }
    ts += __shfl_xor(ts, 32);
    s += ts;
    // ---- pack P to bf16 words, swap halves to build PV A-frags ----
    unsigned int w8[8];
#pragma unroll
    for (int t = 0; t < 8; ++t) {
      union { __bf16 hh[2]; unsigned int u; } pk;
      pk.hh[0] = (__bf16)p[2 * t]; pk.hh[1] = (__bf16)p[2 * t + 1];
      w8[t] = pk.u;
    }
    const unsigned int e0 = __shfl_xor(hi ? w8[0] : w8[2], 32);
    const unsigned int e1 = __shfl_xor(hi ? w8[1] : w8[3], 32);
    const unsigned int e2 = __shfl_xor(hi ? w8[4] : w8[6], 32);
    const unsigned int e3 = __shfl_xor(hi ? w8[5] : w8[7], 32);
    union { unsigned int wd[4]; bf16x8 v; } pa0, pa1;
    if (hi) {
      pa0.wd[0] = e0;    pa0.wd[1] = e1;    pa0.wd[2] = w8[2]; pa0.wd[3] = w8[3];
      pa1.wd[0] = e2;    pa1.wd[1] = e3;    pa1.wd[2] = w8[6]; pa1.wd[3] = w8[7];
    } else {
      pa0.wd[0] = w8[0]; pa0.wd[1] = w8[1]; pa0.wd[2] = e0;    pa0.wd[3] = e1;
      pa1.wd[0] = w8[4]; pa1.wd[1] = w8[5]; pa1.wd[2] = e2;    pa1.wd[3] = e3;
    }
    // ---- PV: O[q][d] += P * V,  V^T[d][s] rows are contiguous in key ----
#pragma unroll
    for (int t = 0; t < 2; ++t) {
      const bf16x8 pa = t ? pa1.v : pa0.v;
      bf16x8 vf0 = *(const bf16x8*)(Vt + (long)lm * 1024 + k0 + t * 16 + hi * 8);
      bf16x8 vf1 = *(const bf16x8*)(Vt + (long)(32 + lm) * 1024 + k0 + t * 16 + hi * 8);
      oacc0 = __builtin_amdgcn_mfma_f32_32x32x16_bf16(pa, vf0, oacc0, 0, 0, 0);
      oacc1 = __builtin_amdgcn_mfma_f32_32x32x16_bf16(pa, vf1, oacc1, 0, 0, 0);
    }
  }
  // ---- normalize + write: O col layout: q = qbw+krow(r,hi), d = dh*32+lm ----
  const float invs = 1.f / s;
#pragma unroll
  for (int r = 0; r < 16; ++r) {
    const int qr = (r & 3) + 8 * (r >> 2) + 4 * hi;
    const float inv = __int_as_float(
        __builtin_amdgcn_ds_bpermute(qr * 4, __float_as_int(invs)));
    const long row = (long)(b * 1024 + qbw + qr) * 1024 + h * 64;
    ob[row + lm]      = (__bf16)(oacc0[r] * inv);
    ob[row + 32 + lm] = (__bf16)(oacc1[r] * inv);
  }
}

// grid (4, B*H), 4 waves. Wave wi handles q-tiles wi and 31-wi => 33 tiles each (balanced).
__global__ void k_attn(const __bf16* __restrict__ qb_, const __bf16* __restrict__ kb,
                       const __bf16* __restrict__ vtb, __bf16* __restrict__ ob) {
  const int l = threadIdx.x & 63, w = threadIdx.x >> 6;
  const int bh = blockIdx.y, b = bh >> 4, h = bh & 15;
  const int wi = blockIdx.x * 4 + w;  // 0..15
  const __bf16* Q  = qb_ + (long)bh * 65536;
  const __bf16* Kh = kb  + (long)bh * 65536;
  const __bf16* Vt = vtb + (long)bh * 65536;
  attn_qtile(Q, Kh, Vt, ob, b, h, wi * 32, l);
  attn_qtile(Q, Kh, Vt, ob, b, h, (31 - wi) * 32, l);
}

extern "C" void kernel_launch(void* const* d_in, const int* in_sizes, int n_in,
                              void* d_out, int out_size, void* d_ws, size_t ws_size,
                              hipStream_t stream) {
  const float* x      = (const float*)d_in[0];
  const float* w_attn = (const float*)d_in[1];
  const float* b_attn = (const float*)d_in[2];
  const float* w_proj = (const float*)d_in[3];
  const float* b_proj = (const float*)d_in[4];
  float* out = (float*)d_out;

  char* ws = (char*)d_ws;
  const size_t SZ_XBF = (size_t)8192 * 1024 * 2;   // 16.8 MB
  __bf16* x_bf = (__bf16*)ws;  ws += SZ_XBF;
  __bf16* wat  = (__bf16*)ws;  ws += (size_t)3072 * 1024 * 2;
  __bf16* wpt  = (__bf16*)ws;  ws += (size_t)1024 * 1024 * 2;
  __bf16* qb   = (__bf16*)ws;  ws += SZ_XBF;       // [B,H,S,D], pre-scaled 1/8
  __bf16* kb   = (__bf16*)ws;  ws += SZ_XBF;       // [B,H,S,D]
  __bf16* vtb  = (__bf16*)ws;  ws += SZ_XBF;       // [B,H,D,S]
  __bf16* obf  = (__bf16*)ws;  ws += SZ_XBF;       // [B,S,NX]

  k_cast<<<8192, 256, 0, stream>>>(x, x_bf, 2097152);
  k_transpose_cast<<<dim3(96, 32), 256, 0, stream>>>(w_attn, wat, 1024, 3072);
  k_transpose_cast<<<dim3(32, 32), 256, 0, stream>>>(w_proj, wpt, 1024, 1024);
  k_gemm_bt<0><<<dim3(24, 64), 256, 0, stream>>>(x_bf, wat, b_attn, 8192, 3072, 1024,
                                                 qb, kb, vtb, nullptr);
  k_attn<<<dim3(4, 128), 256, 0, stream>>>(qb, kb, vtb, obf);
  k_gemm_bt<1><<<dim3(8, 64), 256, 0, stream>>>(obf, wpt, b_proj, 8192, 1024, 1024,
                                                nullptr, nullptr, nullptr, out);
}

// Round 3
// 279.016 us; speedup vs baseline: 1.5895x; 1.0282x over previous
//
#include <hip/hip_runtime.h>
#include <hip/hip_bf16.h>
#include <stdint.h>

// B=8, S=1024, NX=1024, H=16, D=64
typedef __bf16 bf16x8 __attribute__((ext_vector_type(8)));
typedef float  f32x4  __attribute__((ext_vector_type(4)));
typedef float  f32x16 __attribute__((ext_vector_type(16)));

#define BARRIER() asm volatile("s_barrier" ::: "memory")
#define VMCNT(n)  asm volatile("s_waitcnt vmcnt(" #n ")" ::: "memory")

__device__ __forceinline__ void gload_lds16(const void* g, void* l) {
  __builtin_amdgcn_global_load_lds(
      (const __attribute__((address_space(1))) unsigned int*)g,
      (__attribute__((address_space(3))) unsigned int*)l, 16, 0, 0);
}

// ---------------- cast fp32 -> bf16, 4 elems/thread ----------------
__global__ void k_cast(const float* __restrict__ in, __bf16* __restrict__ out, int n4) {
  int i = blockIdx.x * blockDim.x + threadIdx.x;
  if (i >= n4) return;
  float4 v = reinterpret_cast<const float4*>(in)[i];
  union { __bf16 h[4]; uint64_t u; } c;
  c.h[0] = (__bf16)v.x; c.h[1] = (__bf16)v.y; c.h[2] = (__bf16)v.z; c.h[3] = (__bf16)v.w;
  *reinterpret_cast<uint64_t*>(out + 4l * i) = c.u;
}

// ------------- transpose fp32 [R][C] -> bf16 [C][R] ----------------
__global__ void k_transpose_cast(const float* __restrict__ in, __bf16* __restrict__ out,
                                 int R, int C) {
  __shared__ float t[32][33];
  const int tx = threadIdx.x & 31, ty = threadIdx.x >> 5;  // 32 x 8
  const int c0 = blockIdx.x * 32, r0 = blockIdx.y * 32;
#pragma unroll
  for (int rr = 0; rr < 4; ++rr)
    t[ty * 4 + rr][tx] = in[(long)(r0 + ty * 4 + rr) * C + c0 + tx];
  __syncthreads();
#pragma unroll
  for (int rr = 0; rr < 4; ++rr)
    out[(long)(c0 + ty * 4 + rr) * R + r0 + tx] = (__bf16)t[tx][ty * 4 + rr];
}

// ============ pipelined GEMM: C = A[M,K] * Bt[N,K]^T + bias ============
// Tile 256x128, BK=64, 8 waves (2m x 4n), per-wave C = 128x32 (acc[8][2]).
// LDS: 2 buffers x {Ah0(16K), Ah1(16K), B(16K)} = 96 KB.
// A-halves stripe-interleaved: half = (global_stripe)&1, stripe = row>>4.
// Swizzle (T2): byte-col ^= ((row&7)<<4), applied to gload source AND ds_read.
// Pipeline (T3/T4): per K-tile 2 phases; counted vmcnt (4 then 2), never 0 mid-loop.
// MODE 0: scatter -> q[B,H,S,D] (pre-scaled 1/8), k[B,H,S,D], v^T[B,H,D,S]
// MODE 1: fp32 -> fo[M,N]
template <int MODE>
__launch_bounds__(512, 2)
__global__ void k_gemm_p(const __bf16* __restrict__ A, const __bf16* __restrict__ Bt,
                         const float* __restrict__ bias, int M, int N, int K, int NB,
                         __bf16* __restrict__ qo, __bf16* __restrict__ ko,
                         __bf16* __restrict__ vo, float* __restrict__ fo) {
  __shared__ __bf16 lds[2][3][8192];  // [buf][Ah0, Ah1, B], each 128 rows x 64 cols
  const int tid = threadIdx.x;
  const int l = tid & 63, w = tid >> 6;
  const int lm = l & 15, lq = l >> 4;
  const int wm = w >> 2, wn = w & 3;
  const int nwg = gridDim.x;
  const int wg = (blockIdx.x & 7) * (nwg >> 3) + (blockIdx.x >> 3);  // XCD swizzle (nwg%8==0)
  const int bm = wg / NB, bn = wg % NB;
  const int nt = K >> 6;

  // ---- staging addresses (2 x 16B loads per thread per half-tile) ----
  const int rh0 = tid >> 3;                                  // row_h for load 0 (0..63); load1: +64
  const int scol = ((tid & 7) * 16) ^ ((rh0 & 7) << 4);      // pre-swizzled source col-byte
  long a_off[2][2], b_off[2];
#pragma unroll
  for (int h = 0; h < 2; ++h)
#pragma unroll
    for (int li = 0; li < 2; ++li) {
      const int row_h = li * 64 + rh0;
      const int g_r = bm * 256 + ((row_h >> 4) << 5) + h * 16 + (row_h & 15);
      a_off[h][li] = (long)g_r * K + (scol >> 1);
    }
#pragma unroll
  for (int li = 0; li < 2; ++li)
    b_off[li] = (long)(bn * 128 + li * 64 + rh0) * K + (scol >> 1);

#define STAGE_AH(h, buf, t) { \
    gload_lds16(A + a_off[h][0] + (long)(t) * 64, &lds[buf][h][tid * 8]); \
    gload_lds16(A + a_off[h][1] + (long)(t) * 64, &lds[buf][h][4096 + tid * 8]); }
#define STAGE_B(buf, t) { \
    gload_lds16(Bt + b_off[0] + (long)(t) * 64, &lds[buf][2][tid * 8]); \
    gload_lds16(Bt + b_off[1] + (long)(t) * 64, &lds[buf][2][4096 + tid * 8]); }

  // ---- fragment read offsets (element units within a half) ----
  const int aswz = (lm & 7) << 4;  // == (row_h&7)<<4 for all frag reads (row_h low bits = lm)
  // A-frag (mi,ks): half=mi&1, row_h=(wm*4+(mi>>1))*16+lm, colb=ks*64+lq*16
  // B-frag (nj,ks): row_h=wn*32+nj*16+lm, same colb

  f32x4 acc[8][2] = {};

  // ---- prologue: stage tile 0, queue=[B,Ah0,Ah1]; drain B,Ah0 ----
  STAGE_B(0, 0); STAGE_AH(0, 0, 0); STAGE_AH(1, 0, 0);
  VMCNT(2); BARRIER();

  int cur = 0;
  for (int t = 0; t < nt; ++t) {
    const int nxt = cur ^ 1;
    // ======== phase 0: even-mi MFMAs; stage B(t+1),Ah0(t+1) ========
    bf16x8 bf[2][2], ae[4][2];
#pragma unroll
    for (int nj = 0; nj < 2; ++nj)
#pragma unroll
      for (int ks = 0; ks < 2; ++ks) {
        const int rh = wn * 32 + nj * 16 + lm;
        bf[nj][ks] = *(const bf16x8*)&lds[cur][2][rh * 64 + (((ks * 64 + lq * 16) ^ aswz) >> 1)];
      }
#pragma unroll
    for (int me = 0; me < 4; ++me)
#pragma unroll
      for (int ks = 0; ks < 2; ++ks) {
        const int rh = (wm * 4 + me) * 16 + lm;  // mi=2*me -> half 0
        ae[me][ks] = *(const bf16x8*)&lds[cur][0][rh * 64 + (((ks * 64 + lq * 16) ^ aswz) >> 1)];
      }
    if (t + 1 < nt) {
      STAGE_B(nxt, t + 1); STAGE_AH(0, nxt, t + 1);
      VMCNT(4);            // drains Ah1(t) (needed next phase)
    } else {
      VMCNT(0);            // epilogue drain
    }
    BARRIER();
    __builtin_amdgcn_s_setprio(1);
#pragma unroll
    for (int ks = 0; ks < 2; ++ks)
#pragma unroll
      for (int me = 0; me < 4; ++me)
#pragma unroll
        for (int nj = 0; nj < 2; ++nj)
          acc[2 * me][nj] = __builtin_amdgcn_mfma_f32_16x16x32_bf16(ae[me][ks], bf[nj][ks],
                                                                    acc[2 * me][nj], 0, 0, 0);
    __builtin_amdgcn_s_setprio(0);
    BARRIER();
    // ======== phase 1: odd-mi MFMAs; stage Ah1(t+1) ========
    bf16x8 ao[4][2];
#pragma unroll
    for (int mo = 0; mo < 4; ++mo)
#pragma unroll
      for (int ks = 0; ks < 2; ++ks) {
        const int rh = (wm * 4 + mo) * 16 + lm;  // mi=2*mo+1 -> half 1
        ao[mo][ks] = *(const bf16x8*)&lds[cur][1][rh * 64 + (((ks * 64 + lq * 16) ^ aswz) >> 1)];
      }
    if (t + 1 < nt) {
      STAGE_AH(1, nxt, t + 1);
      VMCNT(2);            // drains B(t+1),Ah0(t+1) (needed next phase)
    }
    BARRIER();
    __builtin_amdgcn_s_setprio(1);
#pragma unroll
    for (int ks = 0; ks < 2; ++ks)
#pragma unroll
      for (int mo = 0; mo < 4; ++mo)
#pragma unroll
        for (int nj = 0; nj < 2; ++nj)
          acc[2 * mo + 1][nj] = __builtin_amdgcn_mfma_f32_16x16x32_bf16(ao[mo][ks], bf[nj][ks],
                                                                        acc[2 * mo + 1][nj], 0, 0, 0);
    __builtin_amdgcn_s_setprio(0);
    BARRIER();
    cur = nxt;
  }

  // ---- epilogue ----
  if (MODE == 0) {
#pragma unroll
    for (int nj = 0; nj < 2; ++nj) {
      const int c = bn * 128 + wn * 32 + nj * 16 + lm;
      const float bv = bias[c];
      const int which = c >> 10, cc = c & 1023, hh = cc >> 6, d = cc & 63;
#pragma unroll
      for (int mi = 0; mi < 8; ++mi)
#pragma unroll
        for (int i = 0; i < 4; ++i) {
          const int r = bm * 256 + wm * 128 + mi * 16 + lq * 4 + i;
          const int b = r >> 10, s_ = r & 1023;
          float fv = acc[mi][nj][i] + bv;
          if (which == 0) fv *= 0.125f;  // fold 1/sqrt(D) into Q
          const __bf16 v = (__bf16)fv;
          const long hb = (long)(b * 16 + hh);
          if (which == 0)      qo[(hb * 1024 + s_) * 64 + d] = v;
          else if (which == 1) ko[(hb * 1024 + s_) * 64 + d] = v;
          else                 vo[(hb * 64 + d) * 1024 + s_] = v;
        }
    }
  } else {
#pragma unroll
    for (int nj = 0; nj < 2; ++nj) {
      const int c = bn * 128 + wn * 32 + nj * 16 + lm;
      const float bv = bias[c];
#pragma unroll
      for (int mi = 0; mi < 8; ++mi)
#pragma unroll
        for (int i = 0; i < 4; ++i) {
          const int r = bm * 256 + wm * 128 + mi * 16 + lq * 4 + i;
          fo[(long)r * N + c] = acc[mi][nj][i] + bv;
        }
    }
  }
#undef STAGE_AH
#undef STAGE_B
}

// ---------------- causal flash attention, 32x32 swapped-QK^T, no LDS ----------------
__device__ __forceinline__ void attn_qtile(const __bf16* __restrict__ Q,
                                           const __bf16* __restrict__ Kh,
                                           const __bf16* __restrict__ Vt,
                                           __bf16* __restrict__ ob,
                                           int b, int h, int qbw, int l) {
  const int lm = l & 31, hi = l >> 5;

  bf16x8 qf[4];
#pragma unroll
  for (int ds = 0; ds < 4; ++ds)
    qf[ds] = *(const bf16x8*)(Q + (long)(qbw + lm) * 64 + ds * 16 + hi * 8);

  f32x16 oacc0 = {}, oacc1 = {};
  float m = -__builtin_inff(), s = 0.f;

  const int ntiles = (qbw >> 5) + 1;
  for (int kt = 0; kt < ntiles; ++kt) {
    const int k0 = kt * 32;
    f32x16 st = {};
#pragma unroll
    for (int ds = 0; ds < 4; ++ds) {
      bf16x8 kf = *(const bf16x8*)(Kh + (long)(k0 + lm) * 64 + ds * 16 + hi * 8);
      st = __builtin_amdgcn_mfma_f32_32x32x16_bf16(kf, qf[ds], st, 0, 0, 0);
    }
    if (kt == ntiles - 1) {
      const int q = qbw + lm;
#pragma unroll
      for (int r = 0; r < 16; ++r) {
        const int key = k0 + (r & 3) + 8 * (r >> 2) + 4 * hi;
        if (key > q) st[r] = -__builtin_inff();
      }
    }
    float tm = st[0];
#pragma unroll
    for (int r = 1; r < 16; ++r) tm = fmaxf(tm, st[r]);
    tm = fmaxf(tm, __shfl_xor(tm, 32));
    if (!__all(tm <= m + 8.f)) {   // defer-max
      const float mn = fmaxf(m, tm);
      const float fac = __expf(m - mn);
      m = mn;
      s *= fac;
#pragma unroll
      for (int r = 0; r < 16; ++r) {
        const int qr = (r & 3) + 8 * (r >> 2) + 4 * hi;
        const float fr = __int_as_float(
            __builtin_amdgcn_ds_bpermute(qr * 4, __float_as_int(fac)));
        oacc0[r] *= fr; oacc1[r] *= fr;
      }
    }
    float p[16], ts = 0.f;
#pragma unroll
    for (int r = 0; r < 16; ++r) { p[r] = __expf(st[r] - m); ts += p[r]; }
    ts += __shfl_xor(ts, 32);
    s += ts;
    unsigned int w8[8];
#pragma unroll
    for (int t = 0; t < 8; ++t) {
      union { __bf16 hh[2]; unsigned int u; } pk;
      pk.hh[0] = (__bf16)p[2 * t]; pk.hh[1] = (__bf16)p[2 * t + 1];
      w8[t] = pk.u;
    }
    const unsigned int e0 = __shfl_xor(hi ? w8[0] : w8[2], 32);
    const unsigned int e1 = __shfl_xor(hi ? w8[1] : w8[3], 32);
    const unsigned int e2 = __shfl_xor(hi ? w8[4] : w8[6], 32);
    const unsigned int e3 = __shfl_xor(hi ? w8[5] : w8[7], 32);
    union { unsigned int wd[4]; bf16x8 v; } pa0, pa1;
    if (hi) {
      pa0.wd[0] = e0;    pa0.wd[1] = e1;    pa0.wd[2] = w8[2]; pa0.wd[3] = w8[3];
      pa1.wd[0] = e2;    pa1.wd[1] = e3;    pa1.wd[2] = w8[6]; pa1.wd[3] = w8[7];
    } else {
      pa0.wd[0] = w8[0]; pa0.wd[1] = w8[1]; pa0.wd[2] = e0;    pa0.wd[3] = e1;
      pa1.wd[0] = w8[4]; pa1.wd[1] = w8[5]; pa1.wd[2] = e2;    pa1.wd[3] = e3;
    }
#pragma unroll
    for (int t = 0; t < 2; ++t) {
      const bf16x8 pa = t ? pa1.v : pa0.v;
      bf16x8 vf0 = *(const bf16x8*)(Vt + (long)lm * 1024 + k0 + t * 16 + hi * 8);
      bf16x8 vf1 = *(const bf16x8*)(Vt + (long)(32 + lm) * 1024 + k0 + t * 16 + hi * 8);
      oacc0 = __builtin_amdgcn_mfma_f32_32x32x16_bf16(pa, vf0, oacc0, 0, 0, 0);
      oacc1 = __builtin_amdgcn_mfma_f32_32x32x16_bf16(pa, vf1, oacc1, 0, 0, 0);
    }
  }
  const float invs = 1.f / s;
#pragma unroll
  for (int r = 0; r < 16; ++r) {
    const int qr = (r & 3) + 8 * (r >> 2) + 4 * hi;
    const float inv = __int_as_float(
        __builtin_amdgcn_ds_bpermute(qr * 4, __float_as_int(invs)));
    const long row = (long)(b * 1024 + qbw + qr) * 1024 + h * 64;
    ob[row + lm]      = (__bf16)(oacc0[r] * inv);
    ob[row + 32 + lm] = (__bf16)(oacc1[r] * inv);
  }
}

__global__ void k_attn(const __bf16* __restrict__ qb_, const __bf16* __restrict__ kb,
                       const __bf16* __restrict__ vtb, __bf16* __restrict__ ob) {
  const int l = threadIdx.x & 63, w = threadIdx.x >> 6;
  const int bh = blockIdx.y, b = bh >> 4, h = bh & 15;
  const int wi = blockIdx.x * 4 + w;  // 0..15
  const __bf16* Q  = qb_ + (long)bh * 65536;
  const __bf16* Kh = kb  + (long)bh * 65536;
  const __bf16* Vt = vtb + (long)bh * 65536;
  attn_qtile(Q, Kh, Vt, ob, b, h, wi * 32, l);
  attn_qtile(Q, Kh, Vt, ob, b, h, (31 - wi) * 32, l);
}

extern "C" void kernel_launch(void* const* d_in, const int* in_sizes, int n_in,
                              void* d_out, int out_size, void* d_ws, size_t ws_size,
                              hipStream_t stream) {
  const float* x      = (const float*)d_in[0];
  const float* w_attn = (const float*)d_in[1];
  const float* b_attn = (const float*)d_in[2];
  const float* w_proj = (const float*)d_in[3];
  const float* b_proj = (const float*)d_in[4];
  float* out = (float*)d_out;

  char* ws = (char*)d_ws;
  const size_t SZ_XBF = (size_t)8192 * 1024 * 2;   // 16.8 MB
  __bf16* x_bf = (__bf16*)ws;  ws += SZ_XBF;
  __bf16* wat  = (__bf16*)ws;  ws += (size_t)3072 * 1024 * 2;
  __bf16* wpt  = (__bf16*)ws;  ws += (size_t)1024 * 1024 * 2;
  __bf16* qb   = (__bf16*)ws;  ws += SZ_XBF;       // [B,H,S,D], pre-scaled 1/8
  __bf16* kb   = (__bf16*)ws;  ws += SZ_XBF;       // [B,H,S,D]
  __bf16* vtb  = (__bf16*)ws;  ws += SZ_XBF;       // [B,H,D,S]
  __bf16* obf  = (__bf16*)ws;  ws += SZ_XBF;       // [B,S,NX]

  k_cast<<<8192, 256, 0, stream>>>(x, x_bf, 2097152);
  k_transpose_cast<<<dim3(96, 32), 256, 0, stream>>>(w_attn, wat, 1024, 3072);
  k_transpose_cast<<<dim3(32, 32), 256, 0, stream>>>(w_proj, wpt, 1024, 1024);
  // QKV: M=8192, N=3072 -> 32x24 = 768 blocks (3 exact CU rounds)
  k_gemm_p<0><<<768, 512, 0, stream>>>(x_bf, wat, b_attn, 8192, 3072, 1024, 24,
                                       qb, kb, vtb, nullptr);
  k_attn<<<dim3(4, 128), 256, 0, stream>>>(qb, kb, vtb, obf);
  // proj: M=8192, N=1024 -> 32x8 = 256 blocks (1 exact CU round)
  k_gemm_p<1><<<256, 512, 0, stream>>>(obf, wpt, b_proj, 8192, 1024, 1024, 8,
                                       nullptr, nullptr, nullptr, out);
}